// Round 9
// baseline (4210.480 us; speedup 1.0000x reference)
//
#include <hip/hip_runtime.h>
#include <hip/hip_bf16.h>
#include <stdint.h>

// SubLSTM: T=512, B=64, I=1024, H=1024, G=4096
// Round-9: ALL-REGISTER dataflow, role-specialized waves, ONE barrier/step.
//   - Tagged h exchange (r4 semantics: 8B word = (2bf16)<<32 | step_tag,
//     2-slot rotation, relaxed agent atomics, no ordering waits).
//   - K-split-8 (r8 weights layout): wave w owns K-slice [w*256,(w+1)*256)
//     for ALL 4 gates; w=0..3 -> W_in cols, w=4..7 -> W_rec cols (w*256 lands
//     in [1024,2048) automatically).
//   - Waves 4-7 poll EXACTLY the tagged words their MFMA lanes consume
//     (16 x dwordx4, one base + imm offsets) and pack A-fragments in
//     registers: no h LDS staging, no syncA. They skip the epilogue and
//     start polling t+1 immediately after syncB(t) -> poll overlaps the
//     x-waves' epilogue/publish.
//   - Waves 0-3 load x A-fragments straight from global (L2-warm); write
//     gate partials; after syncB they (threads 0-255) run the epilogue.
//   - Only LDS: gate-partial exchange, double-buffered (2x32KB) so no
//     second barrier is needed (buf[t&1] readers vs buf[(t+1)&1] writers).
// 256 blocks = 4 batch-groups(16 rows) x 64 unit-groups(16 units), 512 thr.

#define T_STEPS 512
#define NBLK 256

typedef short bf16x8 __attribute__((ext_vector_type(8)));
typedef float f32x4 __attribute__((ext_vector_type(4)));
typedef unsigned int u32x4 __attribute__((ext_vector_type(4)));

// ---- ws layout (bytes) ----
#define WS_XBF    0
#define WS_WCAT   67108864
#define WS_HBUF   83886080
#define WS_NEEDED (83886080 + 524288 + 256)

#define LDS_SIZE 65536   // gsm only: [buf2][gate4][wave8][cell256] f32

__device__ __forceinline__ ushort f2bf(float f) {
  uint32_t u = __float_as_uint(f);
  uint32_t r = (u + 0x7fffu + ((u >> 16) & 1u)) >> 16;
  return (ushort)r;
}

__device__ __forceinline__ float sigmoid_f(float x) {
  float e = __builtin_amdgcn_exp2f(-1.44269504f * x);
  return __builtin_amdgcn_rcpf(1.0f + e);
}

// chunk offsets: k8*128 + j*16, k8=0..7, j=0..1
#define PL(i, OFF)                                                        \
  asm volatile("global_load_dwordx4 %0, %1, off offset:" OFF " sc0 sc1"   \
               : "=v"(vv[i]) : "v"(pp))
#define POLL_FENCE() do {                            \
    asm volatile("s_waitcnt vmcnt(0)" ::: "memory"); \
    __builtin_amdgcn_sched_barrier(0);               \
  } while (0)

__global__ void cvt_bf16_kernel(const float* __restrict__ src,
                                ushort* __restrict__ dst, int n4) {
  int i = blockIdx.x * 256 + threadIdx.x;
  if (i >= n4) return;
  float4 v = ((const float4*)src)[i];
  ushort4 o;
  o.x = f2bf(v.x); o.y = f2bf(v.y); o.z = f2bf(v.z); o.w = f2bf(v.w);
  ((ushort4*)dst)[i] = o;
}

// W_cat[g][0:1024] = W_in[g][:], W_cat[g][1024:2048] = W_rec[g][:]
__global__ void build_wcat_kernel(const float* __restrict__ w_in,
                                  const float* __restrict__ w_rec,
                                  ushort* __restrict__ wc) {
  int i = blockIdx.x * 256 + threadIdx.x;
  if (i >= (4096 * 2048) / 4) return;
  int col4 = i & 511;
  int g = i >> 9;
  const float* src = (col4 < 256) ? (w_in + (size_t)g * 1024 + col4 * 4)
                                  : (w_rec + (size_t)g * 1024 + (col4 - 256) * 4);
  float4 v = *(const float4*)src;
  ushort4 o;
  o.x = f2bf(v.x); o.y = f2bf(v.y); o.z = f2bf(v.z); o.w = f2bf(v.w);
  ((ushort4*)wc)[i] = o;
}

// slot0 <- h0 with tag 0; slot1 <- poison tag (never matches; tags 0..512)
__global__ void init_hbuf_kernel(const float* __restrict__ h0,
                                 unsigned long long* __restrict__ hb) {
  int i = blockIdx.x * 256 + threadIdx.x;  // 0..65535
  if (i >= 65536) return;
  if (i < 32768) {
    int row = i >> 9, u2 = i & 511;
    unsigned lo = f2bf(h0[(size_t)row * 1024 + u2 * 2]);
    unsigned hi = f2bf(h0[(size_t)row * 1024 + u2 * 2 + 1]);
    hb[i] = ((unsigned long long)((hi << 16) | lo) << 32) | 0ull;
  } else {
    hb[i] = 0xFFFFFFFFull;
  }
}

__launch_bounds__(512, 2)
__global__ void sublstm_main(const ushort* __restrict__ xb,
                             const ushort* __restrict__ wc,
                             unsigned long long* __restrict__ hb,
                             const float* __restrict__ c0,
                             const float* __restrict__ bias,
                             float* __restrict__ out) {
  extern __shared__ float gsm[];   // [2][4][8][256] f32 = 64KB

  const int tid  = threadIdx.x;
  const int lane = tid & 63;
  const int w    = tid >> 6;          // 0-3 = x waves, 4-7 = h waves
  const int bid  = blockIdx.x;
  const int b0   = (bid & 3) * 16;
  const int j0   = (bid >> 2) * 16;
  const int arow = lane & 15;
  const int q    = lane >> 4;

  // ---- persistent weights (r8 layout, proven): bfrag[gate][k8] =
  //      W_cat row gate*1024+j0+arow, cols w*256 + k8*32 + q*8 ----
  bf16x8 bfrag[4][8];
  {
    const ushort* wbase = wc + (size_t)(j0 + arow) * 2048 + w * 256 + q * 8;
#pragma unroll
    for (int n = 0; n < 4; ++n)
#pragma unroll
      for (int k8 = 0; k8 < 8; ++k8)
        bfrag[n][k8] = *(const bf16x8*)(wbase + (size_t)n * 2097152 + k8 * 32);
  }

  // ---- cell state + bias (threads 0..255 = x-waves run the epilogue) ----
  const int bb = tid >> 4, uu = tid & 15;
  float c_reg = 0.f;
  float bias_r0 = 0.f, bias_r1 = 0.f, bias_r2 = 0.f, bias_r3 = 0.f;
  if (tid < 256) {
    c_reg = c0[(size_t)(b0 + bb) * 1024 + j0 + uu];
    bias_r0 = bias[0 * 1024 + j0 + uu];
    bias_r1 = bias[1 * 1024 + j0 + uu];
    bias_r2 = bias[2 * 1024 + j0 + uu];
    bias_r3 = bias[3 * 1024 + j0 + uu];
  }

  // ---- fixed addressing ----
  // x A-frags: xb[(t*64 + b0 + arow)*1024 + w*256 + q*8 + k8*32]
  const ushort* xp = xb + ((size_t)b0 + arow) * 1024 + w * 256 + q * 8;
  // h polls: hb[slot + (b0+arow)*512 + (w-4)*128 + q*4 + k8*16 + j*2]
  const size_t hwoff = (size_t)(b0 + arow) * 512 + (w - 4) * 128 + q * 4;
  // publish word (threads<256, uu%2==0)
  const int pubw = (b0 + bb) * 512 + ((j0 + uu) >> 1);

  for (int t = 0; t < T_STEPS; ++t) {
    bf16x8 a[8];
    if (w < 4) {
      // ---- x-waves: A-frags straight from global (L2-warm) ----
      const ushort* xq = xp + (size_t)t * 65536;
#pragma unroll
      for (int k8 = 0; k8 < 8; ++k8)
        a[k8] = *(const bf16x8*)(xq + k8 * 32);
    } else {
      // ---- h-waves: poll exactly the words these lanes consume ----
      const unsigned long long* pp = hb + ((t & 1) << 15) + hwoff;
      u32x4 vv[16];
      PL(0, "0");    PL(1, "16");   PL(2, "128");  PL(3, "144");
      PL(4, "256");  PL(5, "272");  PL(6, "384");  PL(7, "400");
      PL(8, "512");  PL(9, "528");  PL(10, "640"); PL(11, "656");
      PL(12, "768"); PL(13, "784"); PL(14, "896"); PL(15, "912");
      POLL_FENCE();
      const unsigned tu = (unsigned)t;
      for (;;) {
        unsigned np = 0;
#pragma unroll
        for (int i = 0; i < 16; ++i)
          if (vv[i].x != tu || vv[i].z != tu) np |= (1u << i);
        if (!np) break;
        __builtin_amdgcn_s_sleep(1);
        if (np & 0x0001u) PL(0, "0");
        if (np & 0x0002u) PL(1, "16");
        if (np & 0x0004u) PL(2, "128");
        if (np & 0x0008u) PL(3, "144");
        if (np & 0x0010u) PL(4, "256");
        if (np & 0x0020u) PL(5, "272");
        if (np & 0x0040u) PL(6, "384");
        if (np & 0x0080u) PL(7, "400");
        if (np & 0x0100u) PL(8, "512");
        if (np & 0x0200u) PL(9, "528");
        if (np & 0x0400u) PL(10, "640");
        if (np & 0x0800u) PL(11, "656");
        if (np & 0x1000u) PL(12, "768");
        if (np & 0x2000u) PL(13, "784");
        if (np & 0x4000u) PL(14, "896");
        if (np & 0x8000u) PL(15, "912");
        POLL_FENCE();
      }
      // pack data dwords -> A-frags (registers only)
#pragma unroll
      for (int k8 = 0; k8 < 8; ++k8) {
        u32x4 d;
        d.x = vv[2 * k8].y;     d.y = vv[2 * k8].w;
        d.z = vv[2 * k8 + 1].y; d.w = vv[2 * k8 + 1].w;
        a[k8] = __builtin_bit_cast(bf16x8, d);
      }
    }

    // ---- MFMA: this wave's K-slice, all 4 gates, A reused 4x ----
    f32x4 acc0 = {0,0,0,0}, acc1 = {0,0,0,0}, acc2 = {0,0,0,0}, acc3 = {0,0,0,0};
#pragma unroll
    for (int k8 = 0; k8 < 8; ++k8) {
      acc0 = __builtin_amdgcn_mfma_f32_16x16x32_bf16(a[k8], bfrag[0][k8], acc0, 0, 0, 0);
      acc1 = __builtin_amdgcn_mfma_f32_16x16x32_bf16(a[k8], bfrag[1][k8], acc1, 0, 0, 0);
      acc2 = __builtin_amdgcn_mfma_f32_16x16x32_bf16(a[k8], bfrag[2][k8], acc2, 0, 0, 0);
      acc3 = __builtin_amdgcn_mfma_f32_16x16x32_bf16(a[k8], bfrag[3][k8], acc3, 0, 0, 0);
    }

    // ---- gate partials -> gsm[t&1][gate][w][cell] ----
    float* gb = gsm + (t & 1) * 8192;
#pragma unroll
    for (int r = 0; r < 4; ++r) {
      int cell = (q * 4 + r) * 16 + arow;
      gb[0 * 2048 + w * 256 + cell] = acc0[r];
      gb[1 * 2048 + w * 256 + cell] = acc1[r];
      gb[2 * 2048 + w * 256 + cell] = acc2[r];
      gb[3 * 2048 + w * 256 + cell] = acc3[r];
    }
    __syncthreads();   // syncB: the ONLY barrier per step

    // ---- epilogue on threads 0..255; h-waves loop straight to poll(t+1) ----
    if (tid < 256) {
      float p0 = bias_r0, p1 = bias_r1, p2 = bias_r2, p3 = bias_r3;
#pragma unroll
      for (int w8 = 0; w8 < 8; ++w8) {
        p0 += gb[0 * 2048 + w8 * 256 + tid];
        p1 += gb[1 * 2048 + w8 * 256 + tid];
        p2 += gb[2 * 2048 + w8 * 256 + tid];
        p3 += gb[3 * 2048 + w8 * 256 + tid];
      }
      float g_in  = sigmoid_f(p0);
      float g_out = sigmoid_f(p1);
      float g_z   = sigmoid_f(p2);
      float g_f   = sigmoid_f(p3);
      c_reg = c_reg * g_f + g_z - g_in;
      float h_new = sigmoid_f(c_reg) - g_out;

      unsigned hbits = (unsigned)f2bf(h_new);
      unsigned pv = (unsigned)__shfl_xor((int)hbits, 1);
      if ((uu & 1) == 0) {
        unsigned hi32 = (pv << 16) | hbits;
        int wi = ((1 - (t & 1)) << 15) + pubw;
        __hip_atomic_store(&hb[wi],
                           ((unsigned long long)hi32 << 32) |
                               (unsigned long long)(unsigned)(t + 1),
                           __ATOMIC_RELAXED, __HIP_MEMORY_SCOPE_AGENT);
      }
      size_t oidx = (size_t)(b0 + bb) * 1024 + j0 + uu;
      out[(size_t)t * 65536 + oidx] = h_new;
      if (t == T_STEPS - 1) {
        out[(size_t)T_STEPS * 65536 + oidx] = h_new;           // hT
        out[(size_t)T_STEPS * 65536 + 65536 + oidx] = c_reg;   // cT
      }
    }
    // gsm race-freedom without a second barrier: step t+1 writes buf
    // (t+1)&1, whose previous readers (epilogue t-1) finished before
    // publish(t-1), which precedes detect(t+1) on every writer's path;
    // x-waves' writes(t+1) follow their own epilogue(t) in program order.
  }
}

extern "C" void kernel_launch(void* const* d_in, const int* in_sizes, int n_in,
                              void* d_out, int out_size, void* d_ws, size_t ws_size,
                              hipStream_t stream) {
  const float* x     = (const float*)d_in[0];
  const float* h0    = (const float*)d_in[1];
  const float* c0    = (const float*)d_in[2];
  const float* w_in  = (const float*)d_in[3];
  const float* biasp = (const float*)d_in[4];
  const float* w_rec = (const float*)d_in[5];
  float* outp = (float*)d_out;

  if (ws_size < (size_t)WS_NEEDED) return;

  uint8_t* ws = (uint8_t*)d_ws;
  ushort* xbp = (ushort*)(ws + WS_XBF);
  ushort* wcp = (ushort*)(ws + WS_WCAT);
  unsigned long long* hbp = (unsigned long long*)(ws + WS_HBUF);

  hipFuncSetAttribute(reinterpret_cast<const void*>(sublstm_main),
                      hipFuncAttributeMaxDynamicSharedMemorySize, LDS_SIZE);

  cvt_bf16_kernel<<<32768, 256, 0, stream>>>(x, xbp, 8388608);
  build_wcat_kernel<<<8192, 256, 0, stream>>>(w_in, w_rec, wcp);
  init_hbuf_kernel<<<256, 256, 0, stream>>>(h0, hbp);

  void* kargs[] = { (void*)&xbp, (void*)&wcp, (void*)&hbp,
                    (void*)&c0,  (void*)&biasp, (void*)&outp };
  hipLaunchCooperativeKernel((void*)sublstm_main, dim3(NBLK), dim3(512),
                             kargs, LDS_SIZE, stream);
}

// Round 10
// 2705.828 us; speedup vs baseline: 1.5561x; 1.5561x over previous
//
#include <hip/hip_runtime.h>
#include <hip/hip_bf16.h>
#include <stdint.h>

// SubLSTM: T=512, B=64, I=1024, H=1024, G=4096
// Round-10 = round-4 skeleton EXACTLY (best: 1524us) + one surgical change:
//   x is PRE-SWIZZLED in ws as per-(t, batch-group) 32KB LDS images (the XOR
//   swizzle applied at conversion time), so in-loop staging is a LINEAR copy
//   done with __builtin_amdgcn_global_load_lds (width 16): fire-and-forget,
//   no dependent ds_write, no vmcnt stall between publish(t) and poll(t+1)
//   (r4's manual staging blocked ~0.3-0.9us on the x load latency there).
//   Waves 4-7 (no epilogue duty) issue the 8 x 1KB loads for t+1 right after
//   their gsm writes; the next poll's vmcnt(0) fence drains them for free.
// Everything else (tagged h words, all-thread batched poll, 2-slot rotation,
// swizzled h staging, K-half x gate waves, publish-first epilogue) is r4.

#define T_STEPS 512
#define NBLK 256

typedef short bf16x8 __attribute__((ext_vector_type(8)));
typedef float f32x4 __attribute__((ext_vector_type(4)));
typedef unsigned int u32x4 __attribute__((ext_vector_type(4)));

// ---- ws layout (bytes) ----
#define WS_XBF    0          // swizzled x tiles: [t][g] 32KB images, 64MB
#define WS_WCAT   67108864
#define WS_HBUF   83886080
#define WS_NEEDED (83886080 + 524288 + 256)

// ---- LDS layout (bytes) ----
#define LDS_X0   0          // x tiles, 2 x 32KB double buffer, swizzled image
#define LDS_H    65536      // h tile, 32KB, swizzled
#define LDS_G    98304      // gate partials, 8KB
#define LDS_SIZE 106496

__device__ __forceinline__ ushort f2bf(float f) {
  uint32_t u = __float_as_uint(f);
  uint32_t r = (u + 0x7fffu + ((u >> 16) & 1u)) >> 16;
  return (ushort)r;
}

__device__ __forceinline__ float sigmoid_f(float x) {
  float e = __builtin_amdgcn_exp2f(-1.44269504f * x);
  return __builtin_amdgcn_rcpf(1.0f + e);
}

// 16B load bypassing L1+L2 (reads the coherence point / MALL).
__device__ __forceinline__ u32x4 poll_load16(const void* p) {
  u32x4 v;
  asm volatile("global_load_dwordx4 %0, %1, off sc0 sc1"
               : "=v"(v) : "v"(p));
  return v;
}
#define POLL_FENCE() do {                            \
    asm volatile("s_waitcnt vmcnt(0)" ::: "memory"); \
    __builtin_amdgcn_sched_barrier(0);               \
  } while (0)

// async 16B global -> LDS (dest = uniform base + lane*16)
#define GLD_LDS(gp, lp)                                                    \
  __builtin_amdgcn_global_load_lds(                                        \
      (const __attribute__((address_space(1))) unsigned int*)(gp),         \
      (__attribute__((address_space(3))) unsigned int*)(lp), 16, 0, 0)

// x -> bf16, pre-swizzled into 32KB images: image (t*4+g)[P] holds
// x[t*64+g*16+(P>>11)][(((P&2047)^(((P>>11)&7)<<4))>>1) ..+8) as bf16.
__global__ void cvt_swz_kernel(const float* __restrict__ src,
                               ushort* __restrict__ dst) {
  int i = blockIdx.x * 256 + threadIdx.x;     // 16B output chunk index
  if (i >= 4194304) return;
  int P    = (i & 2047) * 16;                 // byte offset in image
  int img  = i >> 11;                         // t*4 + g
  int row  = P >> 11;
  int colb = (P & 2047) ^ ((row & 7) << 4);
  int trow = (img >> 2) * 64 + (img & 3) * 16 + row;
  const float* s = src + (size_t)trow * 1024 + (colb >> 1);
  float4 v0 = *(const float4*)s;
  float4 v1 = *(const float4*)(s + 4);
  uint4 o;
  o.x = (unsigned)f2bf(v0.x) | ((unsigned)f2bf(v0.y) << 16);
  o.y = (unsigned)f2bf(v0.z) | ((unsigned)f2bf(v0.w) << 16);
  o.z = (unsigned)f2bf(v1.x) | ((unsigned)f2bf(v1.y) << 16);
  o.w = (unsigned)f2bf(v1.z) | ((unsigned)f2bf(v1.w) << 16);
  ((uint4*)dst)[i] = o;
}

// W_cat[g][0:1024] = W_in[g][:], W_cat[g][1024:2048] = W_rec[g][:]
__global__ void build_wcat_kernel(const float* __restrict__ w_in,
                                  const float* __restrict__ w_rec,
                                  ushort* __restrict__ wc) {
  int i = blockIdx.x * 256 + threadIdx.x;
  if (i >= (4096 * 2048) / 4) return;
  int col4 = i & 511;
  int g = i >> 9;
  const float* src = (col4 < 256) ? (w_in + (size_t)g * 1024 + col4 * 4)
                                  : (w_rec + (size_t)g * 1024 + (col4 - 256) * 4);
  float4 v = *(const float4*)src;
  ushort4 o;
  o.x = f2bf(v.x); o.y = f2bf(v.y); o.z = f2bf(v.z); o.w = f2bf(v.w);
  ((ushort4*)wc)[i] = o;
}

// slot0 <- h0 with tag 0; slot1 <- poison tag (never matches; tags 0..512)
__global__ void init_hbuf_kernel(const float* __restrict__ h0,
                                 unsigned long long* __restrict__ hb) {
  int i = blockIdx.x * 256 + threadIdx.x;  // 0..65535
  if (i >= 65536) return;
  if (i < 32768) {
    int row = i >> 9, u2 = i & 511;
    unsigned lo = f2bf(h0[(size_t)row * 1024 + u2 * 2]);
    unsigned hi = f2bf(h0[(size_t)row * 1024 + u2 * 2 + 1]);
    hb[i] = ((unsigned long long)((hi << 16) | lo) << 32) | 0ull;
  } else {
    hb[i] = 0xFFFFFFFFull;
  }
}

__launch_bounds__(512, 2)
__global__ void sublstm_main(const ushort* __restrict__ xb,
                             const ushort* __restrict__ wc,
                             unsigned long long* __restrict__ hb,
                             const float* __restrict__ c0,
                             const float* __restrict__ bias,
                             float* __restrict__ out) {
  extern __shared__ unsigned char smem[];
  float* gsm = (float*)(smem + LDS_G);
  const unsigned char* xswz = (const unsigned char*)xb;

  const int tid  = threadIdx.x;
  const int lane = tid & 63;
  const int wid  = tid >> 6;
  const int gt   = wid >> 1;   // gate: 0=in 1=out 2=z 3=f
  const int kh   = wid & 1;    // K-half: 0 = x, 1 = h
  const int bid  = blockIdx.x;
  const int b0   = (bid & 3) * 16;
  const int j0   = (bid >> 2) * 16;

  // ---- persistent W_cat B-fragments ----
  bf16x8 bfrag[32];
  {
    const int row_g = gt * 1024 + j0 + (lane & 15);
    const ushort* wrow = wc + (size_t)row_g * 2048 + kh * 1024 + ((lane >> 4) * 8);
#pragma unroll
    for (int ks = 0; ks < 32; ++ks)
      bfrag[ks] = *(const bf16x8*)(wrow + ks * 32);
  }

  // ---- cell state + bias (threads 0..255: (batch bb, unit uu)) ----
  const int bb = tid >> 4, uu = tid & 15;
  float c_reg = 0.f;
  float bias_r0 = 0.f, bias_r1 = 0.f, bias_r2 = 0.f, bias_r3 = 0.f;
  if (tid < 256) {
    c_reg = c0[(size_t)(b0 + bb) * 1024 + j0 + uu];
    bias_r0 = bias[0 * 1024 + j0 + uu];
    bias_r1 = bias[1 * 1024 + j0 + uu];
    bias_r2 = bias[2 * 1024 + j0 + uu];
    bias_r3 = bias[3 * 1024 + j0 + uu];
  }

  // ---- fixed addressing (identical to round-4) ----
  const int prow = tid >> 5;                  // h-poll row 0..15
  const int pc   = tid & 31;                  // h-poll chunk-lane 0..31
  const int arow = lane & 15;
  const int aswz = (arow & 7) << 4;
  const int pswz = (prow & 7) << 4;
  const int basew2 = (b0 + prow) * 512 + pc * 2;   // 8B-word idx (16B aligned)
  const int hbyte  = prow * 2048 + pc * 8;         // LDS byte base for staging
  const int aoff   = arow * 2048 + ((lane >> 4) * 16);

  // ---- prologue: async-stage x_0 image into buffer 0 (waves 4-7) ----
  if (wid >= 4) {
    const unsigned char* sp =
        xswz + ((size_t)(bid & 3) << 15) + (wid - 4) * 8192 + lane * 16;
    unsigned char* dp = smem + (wid - 4) * 8192;
#pragma unroll
    for (int j = 0; j < 8; ++j)
      GLD_LDS(sp + j * 1024, dp + j * 1024);
  }

  for (int t = 0; t < T_STEPS; ++t) {
    // ---- poll h_t: 8 x dwordx4, batched re-poll of pending chunks only ----
    {
      const unsigned long long* pb = hb + ((t & 1) << 15) + basew2;
      u32x4 vv[8];
#pragma unroll
      for (int i = 0; i < 8; ++i) vv[i] = poll_load16(pb + i * 64);
      POLL_FENCE();   // also drains this wave's async x staging loads
      for (;;) {
        unsigned np = 0;
#pragma unroll
        for (int i = 0; i < 8; ++i)
          if ((vv[i].x != (unsigned)t) || (vv[i].z != (unsigned)t))
            np |= (1u << i);
        if (!np) break;
        __builtin_amdgcn_s_sleep(1);
#pragma unroll
        for (int i = 0; i < 8; ++i)
          if (np & (1u << i)) vv[i] = poll_load16(pb + i * 64);
        POLL_FENCE();
      }
      // stage data dwords (2 x bf16 each) -> swizzled LDS h tile
#pragma unroll
      for (int i = 0; i < 8; ++i) {
        uint2 d; d.x = vv[i].y; d.y = vv[i].w;
        *(uint2*)(smem + LDS_H + ((hbyte + i * 256) ^ pswz)) = d;
      }
    }
    __syncthreads();   // syncA: h staged; x image landed (drained above)

    // ---- MFMA over this wave's K-half, 4 independent acc chains ----
    const int abase = (kh ? LDS_H : LDS_X0 + ((t & 1) << 15)) + aoff;
    f32x4 acc0 = {0,0,0,0}, acc1 = {0,0,0,0};
    f32x4 acc2 = {0,0,0,0}, acc3 = {0,0,0,0};
#pragma unroll
    for (int ks = 0; ks < 32; ks += 4) {
      bf16x8 a0 = *(const bf16x8*)(smem + ((abase + (ks + 0) * 64) ^ aswz));
      bf16x8 a1 = *(const bf16x8*)(smem + ((abase + (ks + 1) * 64) ^ aswz));
      bf16x8 a2 = *(const bf16x8*)(smem + ((abase + (ks + 2) * 64) ^ aswz));
      bf16x8 a3 = *(const bf16x8*)(smem + ((abase + (ks + 3) * 64) ^ aswz));
      acc0 = __builtin_amdgcn_mfma_f32_16x16x32_bf16(a0, bfrag[ks + 0], acc0, 0, 0, 0);
      acc1 = __builtin_amdgcn_mfma_f32_16x16x32_bf16(a1, bfrag[ks + 1], acc1, 0, 0, 0);
      acc2 = __builtin_amdgcn_mfma_f32_16x16x32_bf16(a2, bfrag[ks + 2], acc2, 0, 0, 0);
      acc3 = __builtin_amdgcn_mfma_f32_16x16x32_bf16(a3, bfrag[ks + 3], acc3, 0, 0, 0);
    }

    // ---- gate partials -> LDS ----
#pragma unroll
    for (int r = 0; r < 4; ++r)
      gsm[wid * 256 + ((lane >> 4) * 4 + r) * 16 + (lane & 15)] =
          (acc0[r] + acc1[r]) + (acc2[r] + acc3[r]);

    // ---- async-stage x_{t+1} image (waves 4-7; fire-and-forget).
    //      Safe: xbuf[(t+1)&1]'s readers finished before syncB(t-1); loads
    //      drain in next poll's vmcnt(0); visibility via syncA(t+1). ----
    if (wid >= 4 && t + 1 < T_STEPS) {
      const unsigned char* sp = xswz +
          (((size_t)(t + 1) * 4 + (bid & 3)) << 15) + (wid - 4) * 8192 + lane * 16;
      unsigned char* dp = smem + (((t + 1) & 1) << 15) + (wid - 4) * 8192;
#pragma unroll
      for (int j = 0; j < 8; ++j)
        GLD_LDS(sp + j * 1024, dp + j * 1024);
    }
    __syncthreads();   // syncB: all partials in; LDS tile reads done

    // ---- cell update; publish h FIRST, then out (threads 0..255) ----
    if (tid < 256) {
      float p_in  = gsm[0 * 256 + tid] + gsm[1 * 256 + tid] + bias_r0;
      float p_out = gsm[2 * 256 + tid] + gsm[3 * 256 + tid] + bias_r1;
      float p_z   = gsm[4 * 256 + tid] + gsm[5 * 256 + tid] + bias_r2;
      float p_f   = gsm[6 * 256 + tid] + gsm[7 * 256 + tid] + bias_r3;
      float g_in  = sigmoid_f(p_in);
      float g_out = sigmoid_f(p_out);
      float g_z   = sigmoid_f(p_z);
      float g_f   = sigmoid_f(p_f);
      c_reg = c_reg * g_f + g_z - g_in;
      float h_new = sigmoid_f(c_reg) - g_out;

      unsigned hbits = (unsigned)f2bf(h_new);
      unsigned pv = (unsigned)__shfl_xor((int)hbits, 1);
      if ((uu & 1) == 0) {
        unsigned hi32 = (pv << 16) | hbits;
        int wi = ((1 - (t & 1)) << 15) + (b0 + bb) * 512 + ((j0 + uu) >> 1);
        __hip_atomic_store(&hb[wi],
                           ((unsigned long long)hi32 << 32) |
                               (unsigned long long)(unsigned)(t + 1),
                           __ATOMIC_RELAXED, __HIP_MEMORY_SCOPE_AGENT);
      }
      size_t oidx = (size_t)(b0 + bb) * 1024 + j0 + uu;
      out[(size_t)t * 65536 + oidx] = h_new;
      if (t == T_STEPS - 1) {
        out[(size_t)T_STEPS * 65536 + oidx] = h_new;           // hT
        out[(size_t)T_STEPS * 65536 + 65536 + oidx] = c_reg;   // cT
      }
    }
    // no loop-end barrier (r4 reasoning unchanged); x staging for t+1 was
    // issued pre-syncB into the buffer whose readers finished at t-1.
  }
}

extern "C" void kernel_launch(void* const* d_in, const int* in_sizes, int n_in,
                              void* d_out, int out_size, void* d_ws, size_t ws_size,
                              hipStream_t stream) {
  const float* x     = (const float*)d_in[0];
  const float* h0    = (const float*)d_in[1];
  const float* c0    = (const float*)d_in[2];
  const float* w_in  = (const float*)d_in[3];
  const float* biasp = (const float*)d_in[4];
  const float* w_rec = (const float*)d_in[5];
  float* outp = (float*)d_out;

  if (ws_size < (size_t)WS_NEEDED) return;

  uint8_t* ws = (uint8_t*)d_ws;
  ushort* xbp = (ushort*)(ws + WS_XBF);
  ushort* wcp = (ushort*)(ws + WS_WCAT);
  unsigned long long* hbp = (unsigned long long*)(ws + WS_HBUF);

  hipFuncSetAttribute(reinterpret_cast<const void*>(sublstm_main),
                      hipFuncAttributeMaxDynamicSharedMemorySize, LDS_SIZE);

  cvt_swz_kernel<<<16384, 256, 0, stream>>>(x, xbp);
  build_wcat_kernel<<<8192, 256, 0, stream>>>(w_in, w_rec, wcp);
  init_hbuf_kernel<<<256, 256, 0, stream>>>(h0, hbp);

  void* kargs[] = { (void*)&xbp, (void*)&wcp, (void*)&hbp,
                    (void*)&c0,  (void*)&biasp, (void*)&outp };
  hipLaunchCooperativeKernel((void*)sublstm_main, dim3(NBLK), dim3(512),
                             kargs, LDS_SIZE, stream);
}

// Round 11
// 2583.190 us; speedup vs baseline: 1.6300x; 1.0475x over previous
//
#include <hip/hip_runtime.h>
#include <hip/hip_bf16.h>
#include <stdint.h>

// SubLSTM: T=512, B=64, I=1024, H=1024, G=4096
// Round-11 = round-4 (best: 1524us) VERBATIM + one surgical change:
//   SOFTWARE-PIPELINED POLL ISSUE. vv[8] is hoisted out of the t-loop; the
//   8 poll loads for h_{t+1} are issued at the END of step t (right after
//   publish, BEFORE the x staging), so they are in flight during the x-stage
//   (~0.3-0.9us) instead of starting after it. Loop top is fence -> check ->
//   re-poll-pending (identical to r4). Threads >=256 (no epilogue) issue
//   their polls immediately after syncB — earliest possible. No new waits
//   on the publish path; worst case behavior == r4.
// Everything else (tagged h words, 2-slot rotation, swizzled LDS tiles,
// K-half x gate waves, publish-first epilogue, manual x staging) is r4.

#define T_STEPS 512
#define NBLK 256

typedef short bf16x8 __attribute__((ext_vector_type(8)));
typedef float f32x4 __attribute__((ext_vector_type(4)));
typedef unsigned int u32x4 __attribute__((ext_vector_type(4)));

// ---- ws layout (bytes) ----
#define WS_XBF    0
#define WS_WCAT   67108864
#define WS_HBUF   83886080
#define WS_NEEDED (83886080 + 524288 + 256)

// ---- LDS layout (bytes) ----
#define LDS_X0   0          // x tiles, 2 x 32KB double buffer, swizzled
#define LDS_H    65536      // h tile, 32KB, swizzled
#define LDS_G    98304      // gate partials, 8KB
#define LDS_SIZE 106496

__device__ __forceinline__ ushort f2bf(float f) {
  uint32_t u = __float_as_uint(f);
  uint32_t r = (u + 0x7fffu + ((u >> 16) & 1u)) >> 16;
  return (ushort)r;
}

__device__ __forceinline__ float sigmoid_f(float x) {
  float e = __builtin_amdgcn_exp2f(-1.44269504f * x);
  return __builtin_amdgcn_rcpf(1.0f + e);
}

// 16B load bypassing L1+L2 (reads the coherence point / MALL).
__device__ __forceinline__ u32x4 poll_load16(const void* p) {
  u32x4 v;
  asm volatile("global_load_dwordx4 %0, %1, off sc0 sc1"
               : "=v"(v) : "v"(p));
  return v;
}
#define POLL_FENCE() do {                            \
    asm volatile("s_waitcnt vmcnt(0)" ::: "memory"); \
    __builtin_amdgcn_sched_barrier(0);               \
  } while (0)

__global__ void cvt_bf16_kernel(const float* __restrict__ src,
                                ushort* __restrict__ dst, int n4) {
  int i = blockIdx.x * 256 + threadIdx.x;
  if (i >= n4) return;
  float4 v = ((const float4*)src)[i];
  ushort4 o;
  o.x = f2bf(v.x); o.y = f2bf(v.y); o.z = f2bf(v.z); o.w = f2bf(v.w);
  ((ushort4*)dst)[i] = o;
}

// W_cat[g][0:1024] = W_in[g][:], W_cat[g][1024:2048] = W_rec[g][:]
__global__ void build_wcat_kernel(const float* __restrict__ w_in,
                                  const float* __restrict__ w_rec,
                                  ushort* __restrict__ wc) {
  int i = blockIdx.x * 256 + threadIdx.x;
  if (i >= (4096 * 2048) / 4) return;
  int col4 = i & 511;
  int g = i >> 9;
  const float* src = (col4 < 256) ? (w_in + (size_t)g * 1024 + col4 * 4)
                                  : (w_rec + (size_t)g * 1024 + (col4 - 256) * 4);
  float4 v = *(const float4*)src;
  ushort4 o;
  o.x = f2bf(v.x); o.y = f2bf(v.y); o.z = f2bf(v.z); o.w = f2bf(v.w);
  ((ushort4*)wc)[i] = o;
}

// slot0 <- h0 with tag 0; slot1 <- poison tag (never matches; tags 0..512)
__global__ void init_hbuf_kernel(const float* __restrict__ h0,
                                 unsigned long long* __restrict__ hb) {
  int i = blockIdx.x * 256 + threadIdx.x;  // 0..65535
  if (i >= 65536) return;
  if (i < 32768) {
    int row = i >> 9, u2 = i & 511;
    unsigned lo = f2bf(h0[(size_t)row * 1024 + u2 * 2]);
    unsigned hi = f2bf(h0[(size_t)row * 1024 + u2 * 2 + 1]);
    hb[i] = ((unsigned long long)((hi << 16) | lo) << 32) | 0ull;
  } else {
    hb[i] = 0xFFFFFFFFull;
  }
}

__launch_bounds__(512, 2)
__global__ void sublstm_main(const ushort* __restrict__ xb,
                             const ushort* __restrict__ wc,
                             unsigned long long* __restrict__ hb,
                             const float* __restrict__ c0,
                             const float* __restrict__ bias,
                             float* __restrict__ out) {
  extern __shared__ unsigned char smem[];
  float* gsm = (float*)(smem + LDS_G);

  const int tid  = threadIdx.x;
  const int lane = tid & 63;
  const int wid  = tid >> 6;
  const int gt   = wid >> 1;   // gate: 0=in 1=out 2=z 3=f
  const int kh   = wid & 1;    // K-half: 0 = x, 1 = h
  const int bid  = blockIdx.x;
  const int b0   = (bid & 3) * 16;
  const int j0   = (bid >> 2) * 16;

  // ---- persistent W_cat B-fragments ----
  bf16x8 bfrag[32];
  {
    const int row_g = gt * 1024 + j0 + (lane & 15);
    const ushort* wrow = wc + (size_t)row_g * 2048 + kh * 1024 + ((lane >> 4) * 8);
#pragma unroll
    for (int ks = 0; ks < 32; ++ks)
      bfrag[ks] = *(const bf16x8*)(wrow + ks * 32);
  }

  // ---- cell state + bias (threads 0..255: (batch bb, unit uu)) ----
  const int bb = tid >> 4, uu = tid & 15;
  float c_reg = 0.f;
  float bias_r0 = 0.f, bias_r1 = 0.f, bias_r2 = 0.f, bias_r3 = 0.f;
  if (tid < 256) {
    c_reg = c0[(size_t)(b0 + bb) * 1024 + j0 + uu];
    bias_r0 = bias[0 * 1024 + j0 + uu];
    bias_r1 = bias[1 * 1024 + j0 + uu];
    bias_r2 = bias[2 * 1024 + j0 + uu];
    bias_r3 = bias[3 * 1024 + j0 + uu];
  }

  // ---- fixed addressing (identical to round-4) ----
  const int prow = tid >> 5;                  // h-poll row 0..15
  const int pc   = tid & 31;                  // h-poll chunk-lane 0..31
  const int arow = lane & 15;
  const int aswz = (arow & 7) << 4;
  const int pswz = (prow & 7) << 4;
  const int basew2 = (b0 + prow) * 512 + pc * 2;   // 8B-word idx (16B aligned)
  const int hbyte  = prow * 2048 + pc * 8;         // LDS byte base for staging
  const int aoff   = arow * 2048 + ((lane >> 4) * 16);

  // poll state lives ACROSS iterations (software-pipelined issue)
  u32x4 vv[8];
#define ISSUE_POLL(slot)                                                   \
  do {                                                                     \
    const unsigned long long* _pb = hb + ((slot) << 15) + basew2;          \
    _Pragma("unroll")                                                      \
    for (int _i = 0; _i < 8; ++_i) vv[_i] = poll_load16(_pb + _i * 64);    \
  } while (0)

  // ---- prologue: stage x_0 into buffer 0, then issue polls for h_0 ----
  {
    const ushort* xrow = xb + (size_t)b0 * 1024;
#pragma unroll
    for (int j = 0; j < 4; ++j) {
      int L = (tid + j * 512) * 16;            // 0..32767
      int row = L >> 11;
      int colb = L & 2047;
      uint4 v = *(const uint4*)(xrow + (size_t)row * 1024 + (colb >> 1));
      *(uint4*)(smem + (L ^ ((row & 7) << 4))) = v;
    }
  }
  ISSUE_POLL(0);

  for (int t = 0; t < T_STEPS; ++t) {
    // ---- detect h_t from the pre-issued batch; re-poll pending only ----
    {
      const unsigned long long* pb = hb + ((t & 1) << 15) + basew2;
      POLL_FENCE();
      for (;;) {
        unsigned np = 0;
#pragma unroll
        for (int i = 0; i < 8; ++i)
          if ((vv[i].x != (unsigned)t) || (vv[i].z != (unsigned)t))
            np |= (1u << i);
        if (!np) break;
        __builtin_amdgcn_s_sleep(1);
#pragma unroll
        for (int i = 0; i < 8; ++i)
          if (np & (1u << i)) vv[i] = poll_load16(pb + i * 64);
        POLL_FENCE();
      }
      // stage data dwords (2 x bf16 each) -> swizzled LDS h tile
#pragma unroll
      for (int i = 0; i < 8; ++i) {
        uint2 d; d.x = vv[i].y; d.y = vv[i].w;
        *(uint2*)(smem + LDS_H + ((hbyte + i * 256) ^ pswz)) = d;
      }
    }
    __syncthreads();   // syncA: h staged (x staged last step / prologue)

    // ---- MFMA over this wave's K-half, 4 independent acc chains ----
    const int abase = (kh ? LDS_H : LDS_X0 + ((t & 1) << 15)) + aoff;
    f32x4 acc0 = {0,0,0,0}, acc1 = {0,0,0,0};
    f32x4 acc2 = {0,0,0,0}, acc3 = {0,0,0,0};
#pragma unroll
    for (int ks = 0; ks < 32; ks += 4) {
      bf16x8 a0 = *(const bf16x8*)(smem + ((abase + (ks + 0) * 64) ^ aswz));
      bf16x8 a1 = *(const bf16x8*)(smem + ((abase + (ks + 1) * 64) ^ aswz));
      bf16x8 a2 = *(const bf16x8*)(smem + ((abase + (ks + 2) * 64) ^ aswz));
      bf16x8 a3 = *(const bf16x8*)(smem + ((abase + (ks + 3) * 64) ^ aswz));
      acc0 = __builtin_amdgcn_mfma_f32_16x16x32_bf16(a0, bfrag[ks + 0], acc0, 0, 0, 0);
      acc1 = __builtin_amdgcn_mfma_f32_16x16x32_bf16(a1, bfrag[ks + 1], acc1, 0, 0, 0);
      acc2 = __builtin_amdgcn_mfma_f32_16x16x32_bf16(a2, bfrag[ks + 2], acc2, 0, 0, 0);
      acc3 = __builtin_amdgcn_mfma_f32_16x16x32_bf16(a3, bfrag[ks + 3], acc3, 0, 0, 0);
    }

    // ---- gate partials -> LDS ----
#pragma unroll
    for (int r = 0; r < 4; ++r)
      gsm[wid * 256 + ((lane >> 4) * 4 + r) * 16 + (lane & 15)] =
          (acc0[r] + acc1[r]) + (acc2[r] + acc3[r]);
    __syncthreads();   // syncB: MFMA LDS reads + gate writes done

    // ---- cell update; publish h FIRST, then out (threads 0..255) ----
    if (tid < 256) {
      float p_in  = gsm[0 * 256 + tid] + gsm[1 * 256 + tid] + bias_r0;
      float p_out = gsm[2 * 256 + tid] + gsm[3 * 256 + tid] + bias_r1;
      float p_z   = gsm[4 * 256 + tid] + gsm[5 * 256 + tid] + bias_r2;
      float p_f   = gsm[6 * 256 + tid] + gsm[7 * 256 + tid] + bias_r3;
      float g_in  = sigmoid_f(p_in);
      float g_out = sigmoid_f(p_out);
      float g_z   = sigmoid_f(p_z);
      float g_f   = sigmoid_f(p_f);
      c_reg = c_reg * g_f + g_z - g_in;
      float h_new = sigmoid_f(c_reg) - g_out;

      unsigned hbits = (unsigned)f2bf(h_new);
      unsigned pv = (unsigned)__shfl_xor((int)hbits, 1);
      if ((uu & 1) == 0) {
        unsigned hi32 = (pv << 16) | hbits;
        int wi = ((1 - (t & 1)) << 15) + (b0 + bb) * 512 + ((j0 + uu) >> 1);
        __hip_atomic_store(&hb[wi],
                           ((unsigned long long)hi32 << 32) |
                               (unsigned long long)(unsigned)(t + 1),
                           __ATOMIC_RELAXED, __HIP_MEMORY_SCOPE_AGENT);
      }
      size_t oidx = (size_t)(b0 + bb) * 1024 + j0 + uu;
      out[(size_t)t * 65536 + oidx] = h_new;
      if (t == T_STEPS - 1) {
        out[(size_t)T_STEPS * 65536 + oidx] = h_new;           // hT
        out[(size_t)T_STEPS * 65536 + 65536 + oidx] = c_reg;   // cT
      }
    }

    // ---- issue polls for h_{t+1} NOW (in flight during x staging) ----
    if (t + 1 < T_STEPS) ISSUE_POLL((t + 1) & 1);

    // ---- stage x_{t+1} (off critical path; protected by syncA(t+1)) ----
    if (t + 1 < T_STEPS) {
      const ushort* xrow = xb + ((size_t)(t + 1) * 64 + b0) * 1024;
      const int xo = ((t + 1) & 1) << 15;
#pragma unroll
      for (int j = 0; j < 4; ++j) {
        int L = (tid + j * 512) * 16;
        int row = L >> 11;
        int colb = L & 2047;
        uint4 v = *(const uint4*)(xrow + (size_t)row * 1024 + (colb >> 1));
        *(uint4*)(smem + xo + (L ^ ((row & 7) << 4))) = v;
      }
    }
    // no loop-end barrier: staging writes for t+1 only touch regions whose
    // step-t readers finished before syncB(t); gsm reads of step t complete
    // before this thread reaches syncA(t+1).
  }
}

extern "C" void kernel_launch(void* const* d_in, const int* in_sizes, int n_in,
                              void* d_out, int out_size, void* d_ws, size_t ws_size,
                              hipStream_t stream) {
  const float* x     = (const float*)d_in[0];
  const float* h0    = (const float*)d_in[1];
  const float* c0    = (const float*)d_in[2];
  const float* w_in  = (const float*)d_in[3];
  const float* biasp = (const float*)d_in[4];
  const float* w_rec = (const float*)d_in[5];
  float* outp = (float*)d_out;

  if (ws_size < (size_t)WS_NEEDED) return;

  uint8_t* ws = (uint8_t*)d_ws;
  ushort* xbp = (ushort*)(ws + WS_XBF);
  ushort* wcp = (ushort*)(ws + WS_WCAT);
  unsigned long long* hbp = (unsigned long long*)(ws + WS_HBUF);

  hipFuncSetAttribute(reinterpret_cast<const void*>(sublstm_main),
                      hipFuncAttributeMaxDynamicSharedMemorySize, LDS_SIZE);

  cvt_bf16_kernel<<<32768, 256, 0, stream>>>(x, xbp, 8388608);
  build_wcat_kernel<<<8192, 256, 0, stream>>>(w_in, w_rec, wcp);
  init_hbuf_kernel<<<256, 256, 0, stream>>>(h0, hbp);

  void* kargs[] = { (void*)&xbp, (void*)&wcp, (void*)&hbp,
                    (void*)&c0,  (void*)&biasp, (void*)&outp };
  hipLaunchCooperativeKernel((void*)sublstm_main, dim3(NBLK), dim3(512),
                             kargs, LDS_SIZE, stream);
}